// Round 18
// baseline (109.966 us; speedup 1.0000x reference)
//
#include <hip/hip_runtime.h>

#define NB 16
#define NS 1024
#define NHID 64
#define NHEADS 4
#define NDH 16
#define LN_EPS 1e-5f
#define QSCALE 0.18033688011112f   // 0.125 * log2(e): folded into qh -> exp2f

using v4h  = __attribute__((ext_vector_type(4))) _Float16;
using v4f  = __attribute__((ext_vector_type(4))) float;

__device__ __forceinline__ v4h cvt4h(float4 a) {
    v4h r; r[0] = (_Float16)a.x; r[1] = (_Float16)a.y;
    r[2] = (_Float16)a.z; r[3] = (_Float16)a.w; return r;
}

// ---------------------------------------------------------------------------
// Kernel 1 (qkv_mfma, round-11 v1): one wave per 16-row tile, 12 units/wave.
// ---------------------------------------------------------------------------
__global__ __launch_bounds__(256) void qkv_mfma_kernel(
    const float* __restrict__ x,
    const float* __restrict__ Wq, const float* __restrict__ bq,
    const float* __restrict__ Wk, const float* __restrict__ bk,
    const float* __restrict__ Wv, const float* __restrict__ bv,
    _Float16* __restrict__ qh, _Float16* __restrict__ kh,
    _Float16* __restrict__ vt)
{
    const int t = threadIdx.x;
    const int w = t >> 6, l = t & 63;
    const int n16 = l & 15, g = l >> 4;
    const int rt = (int)blockIdx.x * 4 + w;
    const int srow0 = rt * 16;
    const int b = srow0 >> 10, s0 = srow0 & 1023;
    const size_t sg = (size_t)srow0 + n16;

    v4h xa[4];
    #pragma unroll
    for (int kb = 0; kb < 4; ++kb)
        xa[kb] = cvt4h(*(const float4*)&x[sg * 64 + kb * 16 + 4 * g]);

    #pragma unroll
    for (int m = 0; m < 3; ++m) {
        const float* W  = (m == 0) ? Wq : (m == 1) ? Wk : Wv;
        const float* bb = (m == 0) ? bq : (m == 1) ? bk : bv;
        #pragma unroll
        for (int mb = 0; mb < 4; ++mb) {
            const float4 bv4 = *(const float4*)&bb[mb * 16 + 4 * g];
            v4f acc = {bv4.x, bv4.y, bv4.z, bv4.w};
            #pragma unroll
            for (int kb = 0; kb < 4; ++kb) {
                v4h wf = cvt4h(*(const float4*)&W[(size_t)(mb * 16 + n16) * 64 + kb * 16 + 4 * g]);
                acc = __builtin_amdgcn_mfma_f32_16x16x16f16(wf, xa[kb], acc, 0, 0, 0);
            }
            const size_t hb = (size_t)(b * NHEADS + mb);
            if (m == 0) {
                v4h r = {(_Float16)(acc[0] * QSCALE), (_Float16)(acc[1] * QSCALE),
                         (_Float16)(acc[2] * QSCALE), (_Float16)(acc[3] * QSCALE)};
                *(v4h*)&qh[(hb * NS + s0 + n16) * NDH + 4 * g] = r;
            } else if (m == 1) {
                v4h r = {(_Float16)acc[0], (_Float16)acc[1], (_Float16)acc[2], (_Float16)acc[3]};
                *(v4h*)&kh[(hb * NS + s0 + n16) * NDH + 4 * g] = r;
            } else {
                #pragma unroll
                for (int i = 0; i < 4; ++i)
                    vt[(hb * NDH + 4 * g + i) * NS + s0 + n16] = (_Float16)acc[i];
            }
        }
    }
}

// ---------------------------------------------------------------------------
// Kernel 2 (attn_ffn v5): barrier-free K-MAJOR sweep with FULL-LINE writes.
// 512-thr blocks (8 waves), one q-tile; wave w owns 64-k tiles j=w (mod 8),
// ALL 4 heads per wave -> amean head-sum is in-lane; each row gets 256 B of
// contiguous amean per tile iteration (full 128B lines) stored straight from
// registers: no LDS staging, no flush barriers, loads pipeline freely.
// qt pair-swizzle mixes heavy+light tiles on each CU. 6 barriers/block total.
// ---------------------------------------------------------------------------
__global__ __launch_bounds__(512, 8) void attn_ffn_kernel(
    const _Float16* __restrict__ qh, const _Float16* __restrict__ kh,
    const _Float16* __restrict__ vt, const int* __restrict__ lengths,
    const float* __restrict__ x,
    const float* __restrict__ W1, const float* __restrict__ b1,
    const float* __restrict__ W2, const float* __restrict__ b2,
    const float* __restrict__ g1, const float* __restrict__ be1,
    const float* __restrict__ g2, const float* __restrict__ be2,
    float* __restrict__ amean,   // [B,S,S]
    float* __restrict__ y)       // [B,S,64]
{
    __shared__ __align__(16) float obuf[4][4][64][4];   // 16384 B
    __shared__ float zlds[8][4][16];                    //  2048 B
    __shared__ float aout_s[16][68];                    //  4352 B
    __shared__ __align__(16) _Float16 h1s[4][16][20];   //  2560 B
    __shared__ float ln2s[4][16][2];                    //   512 B

    const int t  = threadIdx.x;
    const int w8 = t >> 6;
    const int l  = t & 63;
    const int g = l >> 4, n16 = l & 15;
    const int bx = (int)blockIdx.x;
    const int qt = (bx & 1) ? (63 - (bx >> 1)) : (bx >> 1);  // heavy+light pairs per CU
    const int b  = blockIdx.y;
    const int len = lengths[b];
    const int q0 = qt << 4;
    const int qA_ = q0 + n16;
    const bool qvA = qA_ < len;
    const bool lenFA = len >= q0 + 16;
    const int nkA = (len <= q0) ? 0 : min(q0 + 16, len);
    const int ntA = (nkA + 63) >> 6;

    const size_t bh = (size_t)b * NHEADS;
    v4h Q[4];
    #pragma unroll
    for (int h = 0; h < 4; ++h)
        Q[h] = *(const v4h*)&qh[((bh + h) * NS + qA_) * NDH + 4 * g];

    const v4f z4v = {0.f, 0.f, 0.f, 0.f};

    // ---------------- pass 1: Z per head (barrier-free k-major sweep) -------
    float Z[4] = {0.f, 0.f, 0.f, 0.f};
    for (int j = w8; (j << 6) < nkA; j += 8) {
        const int k0 = j << 6;
        #pragma unroll
        for (int s = 0; s < 4; ++s) {
            const int ks = k0 + (s << 4);
            if (ks < nkA) {
                const bool full = lenFA && (ks + 15 <= q0);
                #pragma unroll
                for (int h = 0; h < 4; ++h) {
                    const v4h K = *(const v4h*)&kh[((bh + h) * NS + ks + n16) * NDH + 4 * g];
                    v4f st = __builtin_amdgcn_mfma_f32_16x16x16f16(K, Q[h], z4v, 0, 0, 0);
                    if (full) {
                        Z[h] += exp2f(st[0]) + exp2f(st[1]) + exp2f(st[2]) + exp2f(st[3]);
                    } else {
                        #pragma unroll
                        for (int i = 0; i < 4; ++i) {
                            int kg = ks + 4 * g + i;
                            Z[h] += (qvA && kg <= qA_) ? exp2f(st[i]) : 0.f;
                        }
                    }
                }
            }
        }
    }
    #pragma unroll
    for (int h = 0; h < 4; ++h) {
        Z[h] += __shfl_xor(Z[h], 16, 64);
        Z[h] += __shfl_xor(Z[h], 32, 64);
    }
    if (l < 16) {
        #pragma unroll
        for (int h = 0; h < 4; ++h) zlds[w8][h][l] = Z[h];
    }
    __syncthreads();
    float iz[4];
    #pragma unroll
    for (int h = 0; h < 4; ++h) {
        float z = 0.f;
        #pragma unroll
        for (int w = 0; w < 8; ++w) z += zlds[w][h][n16];
        iz[h] = (z > 0.f) ? 1.f / z : 0.f;
    }

    // ------- pass 2: P, in-lane head-sum, direct full-line amean stores -----
    v4f O[4] = {z4v, z4v, z4v, z4v};
    for (int j = w8; (j << 6) < nkA; j += 8) {
        const int k0 = j << 6;
        float4 am[4];
        #pragma unroll
        for (int s = 0; s < 4; ++s) {
            am[s] = make_float4(0.f, 0.f, 0.f, 0.f);
            const int ks = k0 + (s << 4);
            if (ks < nkA) {
                const bool full = lenFA && (ks + 15 <= q0);
                #pragma unroll
                for (int h = 0; h < 4; ++h) {
                    const v4h K = *(const v4h*)&kh[((bh + h) * NS + ks + n16) * NDH + 4 * g];
                    const v4h V = *(const v4h*)&vt[((bh + h) * NDH + n16) * NS + ks + 4 * g];
                    v4f st = __builtin_amdgcn_mfma_f32_16x16x16f16(K, Q[h], z4v, 0, 0, 0);
                    float p0, p1, p2, p3;
                    if (full) {
                        p0 = exp2f(st[0]) * iz[h]; p1 = exp2f(st[1]) * iz[h];
                        p2 = exp2f(st[2]) * iz[h]; p3 = exp2f(st[3]) * iz[h];
                    } else {
                        const int kg = ks + 4 * g;
                        p0 = (qvA && kg + 0 <= qA_) ? exp2f(st[0]) * iz[h] : 0.f;
                        p1 = (qvA && kg + 1 <= qA_) ? exp2f(st[1]) * iz[h] : 0.f;
                        p2 = (qvA && kg + 2 <= qA_) ? exp2f(st[2]) * iz[h] : 0.f;
                        p3 = (qvA && kg + 3 <= qA_) ? exp2f(st[3]) * iz[h] : 0.f;
                    }
                    am[s].x += p0; am[s].y += p1; am[s].z += p2; am[s].w += p3;
                    v4h ph = {(_Float16)p0, (_Float16)p1, (_Float16)p2, (_Float16)p3};
                    O[h] = __builtin_amdgcn_mfma_f32_16x16x16f16(ph, V, O[h], 0, 0, 0);
                }
            }
        }
        float* arow = &amean[((size_t)(b * NS + q0 + n16)) * NS + k0];
        #pragma unroll
        for (int s = 0; s < 4; ++s)
            *(float4*)&arow[(s << 4) + 4 * g] =
                make_float4(0.25f * am[s].x, 0.25f * am[s].y,
                            0.25f * am[s].z, 0.25f * am[s].w);
    }

    // ---------------- O cross-wave reduce (2-step via obuf) -----------------
    if (w8 >= 4) {
        #pragma unroll
        for (int h = 0; h < 4; ++h)
            *(float4*)&obuf[w8 - 4][h][l][0] = make_float4(O[h][0], O[h][1], O[h][2], O[h][3]);
    }
    __syncthreads();
    if (w8 < 4) {
        #pragma unroll
        for (int h = 0; h < 4; ++h) {
            float4 o = *(float4*)&obuf[w8][h][l][0];
            O[h][0] += o.x; O[h][1] += o.y; O[h][2] += o.z; O[h][3] += o.w;
        }
        #pragma unroll
        for (int h = 0; h < 4; ++h)
            *(float4*)&obuf[w8][h][l][0] = make_float4(O[h][0], O[h][1], O[h][2], O[h][3]);
    }
    __syncthreads();
    if (w8 < 4) {
        const int h = w8;                      // wave h gathers head h
        float4 s = make_float4(0.f, 0.f, 0.f, 0.f);
        #pragma unroll
        for (int w = 0; w < 4; ++w) {
            float4 o = *(float4*)&obuf[w][h][l][0];
            s.x += o.x; s.y += o.y; s.z += o.z; s.w += o.w;
        }
        aout_s[4 * g + 0][h * 16 + n16] = s.x;
        aout_s[4 * g + 1][h * 16 + n16] = s.y;
        aout_s[4 * g + 2][h * 16 + n16] = s.z;
        aout_s[4 * g + 3][h * 16 + n16] = s.w;
    }
    __syncthreads();

    // ---------------- fused FFN (waves 0-3); zero-fill (waves 4-7) ----------
    const bool fact = w8 < 4;
    const int fw = w8;
    const size_t row = (size_t)(b * NS + q0) + n16;

    v4h n1h[4];
    float4 n1self;
    if (fact) {
        float4 o1f[4];
        #pragma unroll
        for (int kb = 0; kb < 4; ++kb) {
            float4 xv = *(const float4*)&x[row * 64 + kb * 16 + 4 * g];
            float4 av = *(const float4*)&aout_s[n16][kb * 16 + 4 * g];
            o1f[kb] = make_float4(xv.x + av.x, xv.y + av.y, xv.z + av.z, xv.w + av.w);
        }
        float s = 0.f;
        #pragma unroll
        for (int kb = 0; kb < 4; ++kb) s += o1f[kb].x + o1f[kb].y + o1f[kb].z + o1f[kb].w;
        s += __shfl_xor(s, 16, 64); s += __shfl_xor(s, 32, 64);
        const float mu = s * (1.f / 64.f);
        float vs = 0.f;
        #pragma unroll
        for (int kb = 0; kb < 4; ++kb) {
            float a = o1f[kb].x - mu, bb2 = o1f[kb].y - mu, c = o1f[kb].z - mu, d = o1f[kb].w - mu;
            vs += a * a + bb2 * bb2 + c * c + d * d;
        }
        vs += __shfl_xor(vs, 16, 64); vs += __shfl_xor(vs, 32, 64);
        const float rs = rsqrtf(vs * (1.f / 64.f) + LN_EPS);
        #pragma unroll
        for (int kb = 0; kb < 4; ++kb) {
            float4 gv  = *(const float4*)&g1[kb * 16 + 4 * g];
            float4 bev = *(const float4*)&be1[kb * 16 + 4 * g];
            float4 nv;
            nv.x = (o1f[kb].x - mu) * rs * gv.x + bev.x;
            nv.y = (o1f[kb].y - mu) * rs * gv.y + bev.y;
            nv.z = (o1f[kb].z - mu) * rs * gv.z + bev.z;
            nv.w = (o1f[kb].w - mu) * rs * gv.w + bev.w;
            n1h[kb] = cvt4h(nv);
            if (kb == fw) n1self = nv;
        }
        const float4 b1v = *(const float4*)&b1[fw * 16 + 4 * g];
        v4f acc = {b1v.x, b1v.y, b1v.z, b1v.w};
        #pragma unroll
        for (int kb = 0; kb < 4; ++kb) {
            v4h wf = cvt4h(*(const float4*)&W1[(size_t)(fw * 16 + n16) * 64 + kb * 16 + 4 * g]);
            acc = __builtin_amdgcn_mfma_f32_16x16x16f16(wf, n1h[kb], acc, 0, 0, 0);
        }
        v4h hh;
        #pragma unroll
        for (int i = 0; i < 4; ++i) {
            float a = acc[i];
            hh[i] = (_Float16)(0.5f * a * (1.f + erff(a * 0.70710678118654752f)));
        }
        *(v4h*)&h1s[fw][n16][4 * g] = hh;
    } else {
        // waves 4-7: amean zero-fill beyond processed 64-k tiles
        const int kz = ntA << 6;
        const int nz4 = (NS - kz) >> 2;
        const float4 zf = make_float4(0.f, 0.f, 0.f, 0.f);
        const int tt = (w8 - 4) * 64 + l;   // 0..255
        for (int r = 0; r < 16; ++r)
            for (int c4 = tt; c4 < nz4; c4 += 256)
                *(float4*)&amean[((size_t)(b * NS + q0 + r)) * NS + kz + c4 * 4] = zf;
    }
    __syncthreads();

    float4 zrow;
    if (fact) {
        const float4 b2v = *(const float4*)&b2[fw * 16 + 4 * g];
        v4f acc = {b2v.x, b2v.y, b2v.z, b2v.w};
        #pragma unroll
        for (int db = 0; db < 4; ++db) {
            v4h hf = *(const v4h*)&h1s[db][n16][4 * g];
            v4h wf = cvt4h(*(const float4*)&W2[(size_t)(fw * 16 + n16) * 64 + db * 16 + 4 * g]);
            acc = __builtin_amdgcn_mfma_f32_16x16x16f16(wf, hf, acc, 0, 0, 0);
        }
        zrow = make_float4(n1self.x + acc[0], n1self.y + acc[1],
                           n1self.z + acc[2], n1self.w + acc[3]);
        float s2 = zrow.x + zrow.y + zrow.z + zrow.w;
        float q2 = zrow.x * zrow.x + zrow.y * zrow.y + zrow.z * zrow.z + zrow.w * zrow.w;
        s2 += __shfl_xor(s2, 16, 64); s2 += __shfl_xor(s2, 32, 64);
        q2 += __shfl_xor(q2, 16, 64); q2 += __shfl_xor(q2, 32, 64);
        if (g == 0) { ln2s[fw][n16][0] = s2; ln2s[fw][n16][1] = q2; }
    }
    __syncthreads();
    if (fact) {
        const float ts = ln2s[0][n16][0] + ln2s[1][n16][0]
                       + ln2s[2][n16][0] + ln2s[3][n16][0];
        const float tq = ln2s[0][n16][1] + ln2s[1][n16][1]
                       + ln2s[2][n16][1] + ln2s[3][n16][1];
        const float mu2 = ts * (1.f / 64.f);
        const float var2 = tq * (1.f / 64.f) - mu2 * mu2;
        const float rs2 = rsqrtf(var2 + LN_EPS);
        float4 gv  = *(const float4*)&g2[fw * 16 + 4 * g];
        float4 bev = *(const float4*)&be2[fw * 16 + 4 * g];
        float4 yv;
        yv.x = (zrow.x - mu2) * rs2 * gv.x + bev.x;
        yv.y = (zrow.y - mu2) * rs2 * gv.y + bev.y;
        yv.z = (zrow.z - mu2) * rs2 * gv.z + bev.z;
        yv.w = (zrow.w - mu2) * rs2 * gv.w + bev.w;
        *(float4*)&y[row * 64 + fw * 16 + 4 * g] = yv;
    }
}

// ---------------------------------------------------------------------------
extern "C" void kernel_launch(void* const* d_in, const int* in_sizes, int n_in,
                              void* d_out, int out_size, void* d_ws, size_t ws_size,
                              hipStream_t stream) {
    const float* x   = (const float*)d_in[0];
    const int* lengths = (const int*)d_in[1];
    const float* Wq  = (const float*)d_in[3];
    const float* bq  = (const float*)d_in[4];
    const float* Wk  = (const float*)d_in[5];
    const float* bk  = (const float*)d_in[6];
    const float* Wv  = (const float*)d_in[7];
    const float* bv  = (const float*)d_in[8];
    const float* W1  = (const float*)d_in[9];
    const float* b1  = (const float*)d_in[10];
    const float* W2  = (const float*)d_in[11];
    const float* b2  = (const float*)d_in[12];
    const float* g1  = (const float*)d_in[13];
    const float* be1 = (const float*)d_in[14];
    const float* g2  = (const float*)d_in[15];
    const float* be2 = (const float*)d_in[16];

    float* y     = (float*)d_out;                       // [B,S,64]
    float* amean = y + (size_t)NB * NS * NHID;          // [B,S,S]

    const size_t nqkv = (size_t)NB * NHEADS * NS * NDH; // 1,048,576 elems
    _Float16* qhw = (_Float16*)d_ws;                    // f16 [B,NH,S,16] (pre-scaled)
    _Float16* khw = qhw + nqkv;
    _Float16* vtw = khw + nqkv;                         // f16 [B,NH,16,S]

    hipLaunchKernelGGL(qkv_mfma_kernel, dim3(NB * NS / 64), dim3(256), 0, stream,
                       x, Wq, bq, Wk, bk, Wv, bv, qhw, khw, vtw);
    hipLaunchKernelGGL(attn_ffn_kernel, dim3(64, NB), dim3(512), 0, stream,
                       qhw, khw, vtw, lengths, x,
                       W1, b1, W2, b2, g1, be1, g2, be2,
                       amean, y);
}

// Round 19
// 64.379 us; speedup vs baseline: 1.7081x; 1.7081x over previous
//
#include <hip/hip_runtime.h>

#define NB 16
#define NS 1024
#define NHID 64
#define NHEADS 4
#define NDH 16
#define LN_EPS 1e-5f
#define QSCALE 0.18033688011112f   // 0.125 * log2(e): folded into qh -> exp2f

using v4h  = __attribute__((ext_vector_type(4))) _Float16;
using v4f  = __attribute__((ext_vector_type(4))) float;

__device__ __forceinline__ v4h cvt4h(float4 a) {
    v4h r; r[0] = (_Float16)a.x; r[1] = (_Float16)a.y;
    r[2] = (_Float16)a.z; r[3] = (_Float16)a.w; return r;
}

// ---------------------------------------------------------------------------
// Kernel 1 (qkv_mfma, round-11 v1): one wave per 16-row tile, 12 units/wave.
// ---------------------------------------------------------------------------
__global__ __launch_bounds__(256) void qkv_mfma_kernel(
    const float* __restrict__ x,
    const float* __restrict__ Wq, const float* __restrict__ bq,
    const float* __restrict__ Wk, const float* __restrict__ bk,
    const float* __restrict__ Wv, const float* __restrict__ bv,
    _Float16* __restrict__ qh, _Float16* __restrict__ kh,
    _Float16* __restrict__ vt)
{
    const int t = threadIdx.x;
    const int w = t >> 6, l = t & 63;
    const int n16 = l & 15, g = l >> 4;
    const int rt = (int)blockIdx.x * 4 + w;
    const int srow0 = rt * 16;
    const int b = srow0 >> 10, s0 = srow0 & 1023;
    const size_t sg = (size_t)srow0 + n16;

    v4h xa[4];
    #pragma unroll
    for (int kb = 0; kb < 4; ++kb)
        xa[kb] = cvt4h(*(const float4*)&x[sg * 64 + kb * 16 + 4 * g]);

    #pragma unroll
    for (int m = 0; m < 3; ++m) {
        const float* W  = (m == 0) ? Wq : (m == 1) ? Wk : Wv;
        const float* bb = (m == 0) ? bq : (m == 1) ? bk : bv;
        #pragma unroll
        for (int mb = 0; mb < 4; ++mb) {
            const float4 bv4 = *(const float4*)&bb[mb * 16 + 4 * g];
            v4f acc = {bv4.x, bv4.y, bv4.z, bv4.w};
            #pragma unroll
            for (int kb = 0; kb < 4; ++kb) {
                v4h wf = cvt4h(*(const float4*)&W[(size_t)(mb * 16 + n16) * 64 + kb * 16 + 4 * g]);
                acc = __builtin_amdgcn_mfma_f32_16x16x16f16(wf, xa[kb], acc, 0, 0, 0);
            }
            const size_t hb = (size_t)(b * NHEADS + mb);
            if (m == 0) {
                v4h r = {(_Float16)(acc[0] * QSCALE), (_Float16)(acc[1] * QSCALE),
                         (_Float16)(acc[2] * QSCALE), (_Float16)(acc[3] * QSCALE)};
                *(v4h*)&qh[(hb * NS + s0 + n16) * NDH + 4 * g] = r;
            } else if (m == 1) {
                v4h r = {(_Float16)acc[0], (_Float16)acc[1], (_Float16)acc[2], (_Float16)acc[3]};
                *(v4h*)&kh[(hb * NS + s0 + n16) * NDH + 4 * g] = r;
            } else {
                #pragma unroll
                for (int i = 0; i < 4; ++i)
                    vt[(hb * NDH + 4 * g + i) * NS + s0 + n16] = (_Float16)acc[i];
            }
        }
    }
}

// ---------------------------------------------------------------------------
// Kernel 2 (attn_ffn v6): r17 pipeline at 512 threads (8 waves) -> 4 blocks/CU
// for finer backfill against len-imbalance. Wave = (head h = wv&3, k-half
// kq2 = wv>>2): subtiles s = 2*kq2+{0,1} of each 64-k tile. Cross-tile K/V
// register prefetch issued before the per-tile barrier; amean through the
// LDS-staged COALESCED flush (per-instruction contiguity - r16/r18 lesson).
// ---------------------------------------------------------------------------
__global__ __launch_bounds__(512, 8) void attn_ffn_kernel(
    const _Float16* __restrict__ qh, const _Float16* __restrict__ kh,
    const _Float16* __restrict__ vt, const int* __restrict__ lengths,
    const float* __restrict__ x,
    const float* __restrict__ W1, const float* __restrict__ b1,
    const float* __restrict__ W2, const float* __restrict__ b2,
    const float* __restrict__ g1, const float* __restrict__ be1,
    const float* __restrict__ g2, const float* __restrict__ be2,
    float* __restrict__ amean,   // [B,S,S]
    float* __restrict__ y)       // [B,S,64]
{
    __shared__ __align__(16) _Float16 Plds[2][NHEADS][16][72]; // 18432 B (obuf aliases)
    __shared__ float zlds[2][NHEADS][16];                      //   512 B
    __shared__ float aout_s[16][68];                           //  4352 B
    __shared__ __align__(16) _Float16 h1s[4][16][20];          //  2560 B
    __shared__ float ln2s[4][16][2];                           //   512 B

    const int t  = threadIdx.x;
    const int wv = t >> 6;
    const int h   = wv & 3;
    const int kq2 = wv >> 2;               // k-half 0/1
    const int l  = t & 63;
    const int g = l >> 4, n16 = l & 15;
    const int qt = 63 - (int)blockIdx.x;   // heavy tiles dispatch first
    const int b  = blockIdx.y;
    const int len = lengths[b];
    const int q0 = qt << 4;
    const int qA_ = q0 + n16;
    const bool qvA = qA_ < len;
    const bool lenFA = len >= q0 + 16;
    const int nkA = (len <= q0) ? 0 : min(q0 + 16, len);
    const int ntA = (nkA + 63) >> 6;

    const size_t hbase = ((size_t)(b * NHEADS + h)) * NS;
    const size_t vbase = ((size_t)(b * NHEADS + h)) * NDH + n16;
    const v4h QA = *(const v4h*)&qh[(hbase + qA_) * NDH + 4 * g];
    const v4f z4v = {0.f, 0.f, 0.f, 0.f};

    // ---------------- pass 1: Z (barrier-free) ----------------
    float ZA = 0.f;
    for (int tile = 0; tile < ntA; ++tile) {
        #pragma unroll
        for (int si = 0; si < 2; ++si) {
            const int ks = (tile << 6) + ((2 * kq2 + si) << 4);
            if (ks >= nkA) continue;
            const v4h K = *(const v4h*)&kh[(hbase + ks + n16) * NDH + 4 * g];
            v4f st = __builtin_amdgcn_mfma_f32_16x16x16f16(K, QA, z4v, 0, 0, 0);
            if (lenFA && (ks + 15 <= q0)) {
                ZA += exp2f(st[0]) + exp2f(st[1]) + exp2f(st[2]) + exp2f(st[3]);
            } else {
                #pragma unroll
                for (int i = 0; i < 4; ++i) {
                    int kg = ks + 4 * g + i;
                    ZA += (qvA && kg <= qA_) ? exp2f(st[i]) : 0.f;
                }
            }
        }
    }
    ZA += __shfl_xor(ZA, 16, 64); ZA += __shfl_xor(ZA, 32, 64);
    if (l < 16) zlds[kq2][h][l] = ZA;
    __syncthreads();
    const float ztA = zlds[0][h][n16] + zlds[1][h][n16];
    const float izA = (ztA > 0.f) ? 1.f / ztA : 0.f;

    // ------ pass 2: prefetch pipeline, Plds staging, coalesced flush --------
    v4f oA = z4v;
    v4h K0a, V0a, K0b, V0b;
    {   // preload tile 0 (this wave's two subtiles)
        const int ksa = (2 * kq2 + 0) << 4, ksb = (2 * kq2 + 1) << 4;
        if (ksa < nkA) {
            K0a = *(const v4h*)&kh[(hbase + ksa + n16) * NDH + 4 * g];
            V0a = *(const v4h*)&vt[vbase * NS + ksa + 4 * g];
        }
        if (ksb < nkA) {
            K0b = *(const v4h*)&kh[(hbase + ksb + n16) * NDH + 4 * g];
            V0b = *(const v4h*)&vt[vbase * NS + ksb + 4 * g];
        }
    }
    for (int tile = 0; tile < ntA; ++tile) {
        const int k0 = tile << 6;
        const int par = tile & 1;
        // issue next tile's loads first (in flight across the barrier drain)
        v4h K1a, V1a, K1b, V1b;
        {
            const int kna = k0 + 64 + ((2 * kq2 + 0) << 4);
            const int knb = k0 + 64 + ((2 * kq2 + 1) << 4);
            if ((tile + 1 < ntA) && (kna < nkA)) {
                K1a = *(const v4h*)&kh[(hbase + kna + n16) * NDH + 4 * g];
                V1a = *(const v4h*)&vt[vbase * NS + kna + 4 * g];
            }
            if ((tile + 1 < ntA) && (knb < nkA)) {
                K1b = *(const v4h*)&kh[(hbase + knb + n16) * NDH + 4 * g];
                V1b = *(const v4h*)&vt[vbase * NS + knb + 4 * g];
            }
        }
        // compute both subtiles from preloaded registers
        #pragma unroll
        for (int si = 0; si < 2; ++si) {
            const int ks = k0 + ((2 * kq2 + si) << 4);
            v4h ph = {(_Float16)0.f, (_Float16)0.f, (_Float16)0.f, (_Float16)0.f};
            if (ks < nkA) {
                const v4h K = si ? K0b : K0a;
                const v4h V = si ? V0b : V0a;
                v4f st = __builtin_amdgcn_mfma_f32_16x16x16f16(K, QA, z4v, 0, 0, 0);
                float p0, p1, p2, p3;
                if (lenFA && (ks + 15 <= q0)) {
                    p0 = exp2f(st[0]) * izA; p1 = exp2f(st[1]) * izA;
                    p2 = exp2f(st[2]) * izA; p3 = exp2f(st[3]) * izA;
                } else {
                    const int kg = ks + 4 * g;
                    p0 = (qvA && kg + 0 <= qA_) ? exp2f(st[0]) * izA : 0.f;
                    p1 = (qvA && kg + 1 <= qA_) ? exp2f(st[1]) * izA : 0.f;
                    p2 = (qvA && kg + 2 <= qA_) ? exp2f(st[2]) * izA : 0.f;
                    p3 = (qvA && kg + 3 <= qA_) ? exp2f(st[3]) * izA : 0.f;
                }
                ph[0] = (_Float16)p0; ph[1] = (_Float16)p1;
                ph[2] = (_Float16)p2; ph[3] = (_Float16)p3;
                oA = __builtin_amdgcn_mfma_f32_16x16x16f16(ph, V, oA, 0, 0, 0);
            }
            *(v4h*)&Plds[par][h][n16][((2 * kq2 + si) << 4) + 4 * g] = ph;
        }
        K0a = K1a; V0a = V1a; K0b = K1b; V0b = V1b;
        __syncthreads();
        {   // coalesced flush: wave w writes rows {w, w+8}, 64 consecutive f32
            #pragma unroll
            for (int it = 0; it < 2; ++it) {
                const int r = (t >> 6) + 8 * it, c = t & 63;
                float s = (float)Plds[par][0][r][c] + (float)Plds[par][1][r][c]
                        + (float)Plds[par][2][r][c] + (float)Plds[par][3][r][c];
                amean[((size_t)(b * NS + q0 + r)) * NS + k0 + c] = 0.25f * s;
            }
        }
    }
    __syncthreads();   // flush reads done before obuf aliases Plds

    // ---------------- O cross-half reduce (obuf aliases Plds) ---------------
    float (*obuf)[64][4] = (float(*)[64][4])Plds;   // [4][64][4] = 4 KB
    if (kq2 == 1) {
        *(float4*)&obuf[h][l][0] = make_float4(oA[0], oA[1], oA[2], oA[3]);
    }
    __syncthreads();
    if (kq2 == 0) {
        float4 o = *(float4*)&obuf[h][l][0];
        oA[0] += o.x; oA[1] += o.y; oA[2] += o.z; oA[3] += o.w;
        #pragma unroll
        for (int i = 0; i < 4; ++i)
            aout_s[4 * g + i][h * 16 + n16] = oA[i];
    }
    __syncthreads();

    // ---------------- fused FFN (waves 0-3); zero-fill (waves 4-7) ----------
    const bool fact = wv < 4;
    const int fw = wv;
    const size_t row = (size_t)(b * NS + q0) + n16;

    v4h n1h[4];
    float4 n1self;
    if (fact) {
        float4 o1f[4];
        #pragma unroll
        for (int kb = 0; kb < 4; ++kb) {
            float4 xv = *(const float4*)&x[row * 64 + kb * 16 + 4 * g];
            float4 av = *(const float4*)&aout_s[n16][kb * 16 + 4 * g];
            o1f[kb] = make_float4(xv.x + av.x, xv.y + av.y, xv.z + av.z, xv.w + av.w);
        }
        float s = 0.f;
        #pragma unroll
        for (int kb = 0; kb < 4; ++kb) s += o1f[kb].x + o1f[kb].y + o1f[kb].z + o1f[kb].w;
        s += __shfl_xor(s, 16, 64); s += __shfl_xor(s, 32, 64);
        const float mu = s * (1.f / 64.f);
        float vs = 0.f;
        #pragma unroll
        for (int kb = 0; kb < 4; ++kb) {
            float a = o1f[kb].x - mu, bb = o1f[kb].y - mu, c = o1f[kb].z - mu, d = o1f[kb].w - mu;
            vs += a * a + bb * bb + c * c + d * d;
        }
        vs += __shfl_xor(vs, 16, 64); vs += __shfl_xor(vs, 32, 64);
        const float rs = rsqrtf(vs * (1.f / 64.f) + LN_EPS);
        #pragma unroll
        for (int kb = 0; kb < 4; ++kb) {
            float4 gv  = *(const float4*)&g1[kb * 16 + 4 * g];
            float4 bev = *(const float4*)&be1[kb * 16 + 4 * g];
            float4 nv;
            nv.x = (o1f[kb].x - mu) * rs * gv.x + bev.x;
            nv.y = (o1f[kb].y - mu) * rs * gv.y + bev.y;
            nv.z = (o1f[kb].z - mu) * rs * gv.z + bev.z;
            nv.w = (o1f[kb].w - mu) * rs * gv.w + bev.w;
            n1h[kb] = cvt4h(nv);
            if (kb == fw) n1self = nv;   // compile-time kb vs wave-uniform fw
        }
        const float4 b1v = *(const float4*)&b1[fw * 16 + 4 * g];
        v4f acc = {b1v.x, b1v.y, b1v.z, b1v.w};
        #pragma unroll
        for (int kb = 0; kb < 4; ++kb) {
            v4h wf = cvt4h(*(const float4*)&W1[(size_t)(fw * 16 + n16) * 64 + kb * 16 + 4 * g]);
            acc = __builtin_amdgcn_mfma_f32_16x16x16f16(wf, n1h[kb], acc, 0, 0, 0);
        }
        v4h hh;
        #pragma unroll
        for (int i = 0; i < 4; ++i) {
            float a = acc[i];
            hh[i] = (_Float16)(0.5f * a * (1.f + erff(a * 0.70710678118654752f)));
        }
        *(v4h*)&h1s[fw][n16][4 * g] = hh;
    } else {
        // waves 4-7: amean zero-fill beyond processed tiles
        const int kz = ntA << 6;
        const int nz4 = (NS - kz) >> 2;
        const float4 zf = make_float4(0.f, 0.f, 0.f, 0.f);
        const int tt = (wv - 4) * 64 + l;   // 0..255
        for (int r = 0; r < 16; ++r)
            for (int c4 = tt; c4 < nz4; c4 += 256)
                *(float4*)&amean[((size_t)(b * NS + q0 + r)) * NS + kz + c4 * 4] = zf;
    }
    __syncthreads();

    float4 zrow;
    if (fact) {
        const float4 b2v = *(const float4*)&b2[fw * 16 + 4 * g];
        v4f acc = {b2v.x, b2v.y, b2v.z, b2v.w};
        #pragma unroll
        for (int db = 0; db < 4; ++db) {
            v4h hf = *(const v4h*)&h1s[db][n16][4 * g];
            v4h wf = cvt4h(*(const float4*)&W2[(size_t)(fw * 16 + n16) * 64 + db * 16 + 4 * g]);
            acc = __builtin_amdgcn_mfma_f32_16x16x16f16(wf, hf, acc, 0, 0, 0);
        }
        zrow = make_float4(n1self.x + acc[0], n1self.y + acc[1],
                           n1self.z + acc[2], n1self.w + acc[3]);
        float s2 = zrow.x + zrow.y + zrow.z + zrow.w;
        float q2 = zrow.x * zrow.x + zrow.y * zrow.y + zrow.z * zrow.z + zrow.w * zrow.w;
        s2 += __shfl_xor(s2, 16, 64); s2 += __shfl_xor(s2, 32, 64);
        q2 += __shfl_xor(q2, 16, 64); q2 += __shfl_xor(q2, 32, 64);
        if (g == 0) { ln2s[fw][n16][0] = s2; ln2s[fw][n16][1] = q2; }
    }
    __syncthreads();
    if (fact) {
        const float ts = ln2s[0][n16][0] + ln2s[1][n16][0]
                       + ln2s[2][n16][0] + ln2s[3][n16][0];
        const float tq = ln2s[0][n16][1] + ln2s[1][n16][1]
                       + ln2s[2][n16][1] + ln2s[3][n16][1];
        const float mu2 = ts * (1.f / 64.f);
        const float var2 = tq * (1.f / 64.f) - mu2 * mu2;
        const float rs2 = rsqrtf(var2 + LN_EPS);
        float4 gv  = *(const float4*)&g2[fw * 16 + 4 * g];
        float4 bev = *(const float4*)&be2[fw * 16 + 4 * g];
        float4 yv;
        yv.x = (zrow.x - mu2) * rs2 * gv.x + bev.x;
        yv.y = (zrow.y - mu2) * rs2 * gv.y + bev.y;
        yv.z = (zrow.z - mu2) * rs2 * gv.z + bev.z;
        yv.w = (zrow.w - mu2) * rs2 * gv.w + bev.w;
        *(float4*)&y[row * 64 + fw * 16 + 4 * g] = yv;
    }
}

// ---------------------------------------------------------------------------
extern "C" void kernel_launch(void* const* d_in, const int* in_sizes, int n_in,
                              void* d_out, int out_size, void* d_ws, size_t ws_size,
                              hipStream_t stream) {
    const float* x   = (const float*)d_in[0];
    const int* lengths = (const int*)d_in[1];
    const float* Wq  = (const float*)d_in[3];
    const float* bq  = (const float*)d_in[4];
    const float* Wk  = (const float*)d_in[5];
    const float* bk  = (const float*)d_in[6];
    const float* Wv  = (const float*)d_in[7];
    const float* bv  = (const float*)d_in[8];
    const float* W1  = (const float*)d_in[9];
    const float* b1  = (const float*)d_in[10];
    const float* W2  = (const float*)d_in[11];
    const float* b2  = (const float*)d_in[12];
    const float* g1  = (const float*)d_in[13];
    const float* be1 = (const float*)d_in[14];
    const float* g2  = (const float*)d_in[15];
    const float* be2 = (const float*)d_in[16];

    float* y     = (float*)d_out;                       // [B,S,64]
    float* amean = y + (size_t)NB * NS * NHID;          // [B,S,S]

    const size_t nqkv = (size_t)NB * NHEADS * NS * NDH; // 1,048,576 elems
    _Float16* qhw = (_Float16*)d_ws;                    // f16 [B,NH,S,16] (pre-scaled)
    _Float16* khw = qhw + nqkv;
    _Float16* vtw = khw + nqkv;                         // f16 [B,NH,16,S]

    hipLaunchKernelGGL(qkv_mfma_kernel, dim3(NB * NS / 64), dim3(256), 0, stream,
                       x, Wq, bq, Wk, bk, Wv, bv, qhw, khw, vtw);
    hipLaunchKernelGGL(attn_ffn_kernel, dim3(64, NB), dim3(512), 0, stream,
                       qhw, khw, vtw, lengths, x,
                       W1, b1, W2, b2, g1, be1, g2, be2,
                       amean, y);
}

// Round 20
// 51.736 us; speedup vs baseline: 2.1255x; 1.2444x over previous
//
#include <hip/hip_runtime.h>

#define NB 16
#define NS 1024
#define NHID 64
#define NHEADS 4
#define NDH 16
#define LN_EPS 1e-5f
#define QSCALE 0.18033688011112f   // 0.125 * log2(e): folded into qh -> exp2f

using v4h  = __attribute__((ext_vector_type(4))) _Float16;
using v4f  = __attribute__((ext_vector_type(4))) float;

__device__ __forceinline__ v4h cvt4h(float4 a) {
    v4h r; r[0] = (_Float16)a.x; r[1] = (_Float16)a.y;
    r[2] = (_Float16)a.z; r[3] = (_Float16)a.w; return r;
}

// ---------------------------------------------------------------------------
// Kernel 1 (qkv_mfma, round-11 v1): one wave per 16-row tile, 12 units/wave.
// ---------------------------------------------------------------------------
__global__ __launch_bounds__(256) void qkv_mfma_kernel(
    const float* __restrict__ x,
    const float* __restrict__ Wq, const float* __restrict__ bq,
    const float* __restrict__ Wk, const float* __restrict__ bk,
    const float* __restrict__ Wv, const float* __restrict__ bv,
    _Float16* __restrict__ qh, _Float16* __restrict__ kh,
    _Float16* __restrict__ vt)
{
    const int t = threadIdx.x;
    const int w = t >> 6, l = t & 63;
    const int n16 = l & 15, g = l >> 4;
    const int rt = (int)blockIdx.x * 4 + w;
    const int srow0 = rt * 16;
    const int b = srow0 >> 10, s0 = srow0 & 1023;
    const size_t sg = (size_t)srow0 + n16;

    v4h xa[4];
    #pragma unroll
    for (int kb = 0; kb < 4; ++kb)
        xa[kb] = cvt4h(*(const float4*)&x[sg * 64 + kb * 16 + 4 * g]);

    #pragma unroll
    for (int m = 0; m < 3; ++m) {
        const float* W  = (m == 0) ? Wq : (m == 1) ? Wk : Wv;
        const float* bb = (m == 0) ? bq : (m == 1) ? bk : bv;
        #pragma unroll
        for (int mb = 0; mb < 4; ++mb) {
            const float4 bv4 = *(const float4*)&bb[mb * 16 + 4 * g];
            v4f acc = {bv4.x, bv4.y, bv4.z, bv4.w};
            #pragma unroll
            for (int kb = 0; kb < 4; ++kb) {
                v4h wf = cvt4h(*(const float4*)&W[(size_t)(mb * 16 + n16) * 64 + kb * 16 + 4 * g]);
                acc = __builtin_amdgcn_mfma_f32_16x16x16f16(wf, xa[kb], acc, 0, 0, 0);
            }
            const size_t hb = (size_t)(b * NHEADS + mb);
            if (m == 0) {
                v4h r = {(_Float16)(acc[0] * QSCALE), (_Float16)(acc[1] * QSCALE),
                         (_Float16)(acc[2] * QSCALE), (_Float16)(acc[3] * QSCALE)};
                *(v4h*)&qh[(hb * NS + s0 + n16) * NDH + 4 * g] = r;
            } else if (m == 1) {
                v4h r = {(_Float16)acc[0], (_Float16)acc[1], (_Float16)acc[2], (_Float16)acc[3]};
                *(v4h*)&kh[(hb * NS + s0 + n16) * NDH + 4 * g] = r;
            } else {
                #pragma unroll
                for (int i = 0; i < 4; ++i)
                    vt[(hb * NDH + 4 * g + i) * NS + s0 + n16] = (_Float16)acc[i];
            }
        }
    }
}

// ---------------------------------------------------------------------------
// Kernel 2 (attn_ffn v7): SINGLE k-sweep via deferred normalization.
// 1024 thr, 16 waves = (head h, k-quarter kq). One sweep computes unnorm
// p~ = exp2(st) (f16-safe), Z, and O~ = sum p~ V; p~ kept in registers
// (preg[16], statically indexed full unroll). Then iz table -> flush-only
// pass writes p~*iz through the proven coalesced LDS flush; O = O~*iz at
// the epilogue. Z-pass deleted: half the K/V loads, QK MFMAs, exps.
// ---------------------------------------------------------------------------
__global__ __launch_bounds__(1024, 8) void attn_ffn_kernel(
    const _Float16* __restrict__ qh, const _Float16* __restrict__ kh,
    const _Float16* __restrict__ vt, const int* __restrict__ lengths,
    const float* __restrict__ x,
    const float* __restrict__ W1, const float* __restrict__ b1,
    const float* __restrict__ W2, const float* __restrict__ b2,
    const float* __restrict__ g1, const float* __restrict__ be1,
    const float* __restrict__ g2, const float* __restrict__ be2,
    float* __restrict__ amean,   // [B,S,S]
    float* __restrict__ y)       // [B,S,64]
{
    __shared__ __align__(16) _Float16 Plds[4][NHEADS][16][72]; // 36864 B (obuf aliases)
    __shared__ float zlds[4][NHEADS][16];                      //  1024 B
    __shared__ float iz_s[NHEADS][16];                         //   256 B
    __shared__ float aout_s[16][68];                           //  4352 B
    __shared__ __align__(16) _Float16 h1s[4][16][20];          //  2560 B
    __shared__ float ln2s[4][16][2];                           //   512 B

    const int t  = threadIdx.x;
    const int wv = t >> 6;
    const int h  = wv & 3;
    const int kq = wv >> 2;
    const int l  = t & 63;
    const int g = l >> 4, n16 = l & 15;
    const int qt = 63 - (int)blockIdx.x;   // heavy tiles dispatch first
    const int b  = blockIdx.y;
    const int len = lengths[b];
    const int q0 = qt << 4;
    const int qA_ = q0 + n16;
    const bool qvA = qA_ < len;
    const bool lenFA = len >= q0 + 16;
    const int nkA = (len <= q0) ? 0 : min(q0 + 16, len);
    const int ntA = (nkA + 63) >> 6;

    const size_t hbase = ((size_t)(b * NHEADS + h)) * NS;
    const size_t vbase = ((size_t)(b * NHEADS + h)) * NDH + n16;
    const v4h QA = *(const v4h*)&qh[(hbase + qA_) * NDH + 4 * g];
    const v4f z4v = {0.f, 0.f, 0.f, 0.f};
    const int pc = (kq << 4) + 4 * g;

    // ------------- single sweep: unnorm p~, Z, O~ (no barriers) -------------
    float ZA = 0.f;
    v4f oA = z4v;
    v4h preg[16];
    #pragma unroll
    for (int tile = 0; tile < 16; ++tile) {
        v4h ph = {(_Float16)0.f, (_Float16)0.f, (_Float16)0.f, (_Float16)0.f};
        const int ks = (tile << 6) + (kq << 4);
        if (tile < ntA && ks < nkA) {
            const v4h K = *(const v4h*)&kh[(hbase + ks + n16) * NDH + 4 * g];
            const v4h V = *(const v4h*)&vt[vbase * NS + ks + 4 * g];
            v4f st = __builtin_amdgcn_mfma_f32_16x16x16f16(K, QA, z4v, 0, 0, 0);
            float p0, p1, p2, p3;
            if (lenFA && (ks + 15 <= q0)) {
                p0 = exp2f(st[0]); p1 = exp2f(st[1]);
                p2 = exp2f(st[2]); p3 = exp2f(st[3]);
            } else {
                const int kg = ks + 4 * g;
                p0 = (qvA && kg + 0 <= qA_) ? exp2f(st[0]) : 0.f;
                p1 = (qvA && kg + 1 <= qA_) ? exp2f(st[1]) : 0.f;
                p2 = (qvA && kg + 2 <= qA_) ? exp2f(st[2]) : 0.f;
                p3 = (qvA && kg + 3 <= qA_) ? exp2f(st[3]) : 0.f;
            }
            ZA += p0 + p1 + p2 + p3;
            ph[0] = (_Float16)p0; ph[1] = (_Float16)p1;
            ph[2] = (_Float16)p2; ph[3] = (_Float16)p3;
            oA = __builtin_amdgcn_mfma_f32_16x16x16f16(ph, V, oA, 0, 0, 0);
        }
        preg[tile] = ph;
    }
    ZA += __shfl_xor(ZA, 16, 64); ZA += __shfl_xor(ZA, 32, 64);
    if (l < 16) zlds[kq][h][l] = ZA;
    __syncthreads();
    if (t < 64) {                           // iz table (visible after next barrier)
        const int hh = t >> 4, qq = t & 15;
        const float z = zlds[0][hh][qq] + zlds[1][hh][qq]
                      + zlds[2][hh][qq] + zlds[3][hh][qq];
        iz_s[hh][qq] = (z > 0.f) ? 1.f / z : 0.f;
    }

    // ------------- flush-only pass: p~ -> Plds, normalize at flush ----------
    #pragma unroll
    for (int tile = 0; tile < 16; ++tile) {
        const int buf = tile & 3;
        if (tile < ntA)
            *(v4h*)&Plds[buf][h][n16][pc] = preg[tile];
        if ((tile & 1) == 1 && (tile - 1) < ntA) {   // block-uniform condition
            __syncthreads();
            const int r = t >> 6, c = t & 63;        // wave = row r
            const float i0 = iz_s[0][r], i1 = iz_s[1][r],
                        i2 = iz_s[2][r], i3 = iz_s[3][r];
            #pragma unroll
            for (int it = 0; it < 2; ++it) {
                const int tf = tile - 1 + it;
                if (tf < ntA) {
                    const int bf = tf & 3;
                    float s = (float)Plds[bf][0][r][c] * i0
                            + (float)Plds[bf][1][r][c] * i1
                            + (float)Plds[bf][2][r][c] * i2
                            + (float)Plds[bf][3][r][c] * i3;
                    amean[((size_t)(b * NS + q0 + r)) * NS + (tf << 6) + c] = 0.25f * s;
                }
            }
        }
    }
    __syncthreads();   // all flush reads done before obuf aliases Plds

    // ---------------- O cross-kq reduce + normalize (obuf aliases Plds) -----
    float* obuf = (float*)Plds;            // 16*64*4 f32 = 16 KB < 36 KB
    {
        float* p = &obuf[(wv * 64 + l) * 4];
        p[0] = oA[0]; p[1] = oA[1]; p[2] = oA[2]; p[3] = oA[3];
    }
    __syncthreads();
    if (kq == 0) {
        #pragma unroll
        for (int kq2 = 1; kq2 < 4; ++kq2) {
            const float* p = &obuf[(((h + 4 * kq2) * 64) + l) * 4];
            oA[0] += p[0]; oA[1] += p[1]; oA[2] += p[2]; oA[3] += p[3];
        }
        #pragma unroll
        for (int i = 0; i < 4; ++i)
            aout_s[4 * g + i][h * 16 + n16] = oA[i] * iz_s[h][4 * g + i];
    }
    __syncthreads();

    // ---------------- fused FFN (waves 0-3); zero-fill (waves 4-15) --------
    const bool fact = wv < 4;
    const int fw = wv;
    const size_t row = (size_t)(b * NS + q0) + n16;

    v4h n1h[4];
    float4 n1self;
    if (fact) {
        float4 o1f[4];
        #pragma unroll
        for (int kb = 0; kb < 4; ++kb) {
            float4 xv = *(const float4*)&x[row * 64 + kb * 16 + 4 * g];
            float4 av = *(const float4*)&aout_s[n16][kb * 16 + 4 * g];
            o1f[kb] = make_float4(xv.x + av.x, xv.y + av.y, xv.z + av.z, xv.w + av.w);
        }
        float s = 0.f;
        #pragma unroll
        for (int kb = 0; kb < 4; ++kb) s += o1f[kb].x + o1f[kb].y + o1f[kb].z + o1f[kb].w;
        s += __shfl_xor(s, 16, 64); s += __shfl_xor(s, 32, 64);
        const float mu = s * (1.f / 64.f);
        float vs = 0.f;
        #pragma unroll
        for (int kb = 0; kb < 4; ++kb) {
            float a = o1f[kb].x - mu, bb = o1f[kb].y - mu, c = o1f[kb].z - mu, d = o1f[kb].w - mu;
            vs += a * a + bb * bb + c * c + d * d;
        }
        vs += __shfl_xor(vs, 16, 64); vs += __shfl_xor(vs, 32, 64);
        const float rs = rsqrtf(vs * (1.f / 64.f) + LN_EPS);
        #pragma unroll
        for (int kb = 0; kb < 4; ++kb) {
            float4 gv  = *(const float4*)&g1[kb * 16 + 4 * g];
            float4 bev = *(const float4*)&be1[kb * 16 + 4 * g];
            float4 nv;
            nv.x = (o1f[kb].x - mu) * rs * gv.x + bev.x;
            nv.y = (o1f[kb].y - mu) * rs * gv.y + bev.y;
            nv.z = (o1f[kb].z - mu) * rs * gv.z + bev.z;
            nv.w = (o1f[kb].w - mu) * rs * gv.w + bev.w;
            n1h[kb] = cvt4h(nv);
            if (kb == fw) n1self = nv;   // compile-time kb vs wave-uniform fw
        }
        const float4 b1v = *(const float4*)&b1[fw * 16 + 4 * g];
        v4f acc = {b1v.x, b1v.y, b1v.z, b1v.w};
        #pragma unroll
        for (int kb = 0; kb < 4; ++kb) {
            v4h wf = cvt4h(*(const float4*)&W1[(size_t)(fw * 16 + n16) * 64 + kb * 16 + 4 * g]);
            acc = __builtin_amdgcn_mfma_f32_16x16x16f16(wf, n1h[kb], acc, 0, 0, 0);
        }
        v4h hh;
        #pragma unroll
        for (int i = 0; i < 4; ++i) {
            float a = acc[i];
            hh[i] = (_Float16)(0.5f * a * (1.f + erff(a * 0.70710678118654752f)));
        }
        *(v4h*)&h1s[fw][n16][4 * g] = hh;
    } else {
        // waves 4-15: amean zero-fill beyond processed tiles (overlaps GEMM1)
        const int kz = ntA << 6;
        const int nz4 = (NS - kz) >> 2;
        const float4 zf = make_float4(0.f, 0.f, 0.f, 0.f);
        const int tt = (wv - 4) * 64 + l;   // 0..767
        for (int r = 0; r < 16; ++r)
            for (int c4 = tt; c4 < nz4; c4 += 768)
                *(float4*)&amean[((size_t)(b * NS + q0 + r)) * NS + kz + c4 * 4] = zf;
    }
    __syncthreads();

    float4 zrow;
    if (fact) {
        const float4 b2v = *(const float4*)&b2[fw * 16 + 4 * g];
        v4f acc = {b2v.x, b2v.y, b2v.z, b2v.w};
        #pragma unroll
        for (int db = 0; db < 4; ++db) {
            v4h hf = *(const v4h*)&h1s[db][n16][4 * g];
            v4h wf = cvt4h(*(const float4*)&W2[(size_t)(fw * 16 + n16) * 64 + db * 16 + 4 * g]);
            acc = __builtin_amdgcn_mfma_f32_16x16x16f16(wf, hf, acc, 0, 0, 0);
        }
        zrow = make_float4(n1self.x + acc[0], n1self.y + acc[1],
                           n1self.z + acc[2], n1self.w + acc[3]);
        float s2 = zrow.x + zrow.y + zrow.z + zrow.w;
        float q2 = zrow.x * zrow.x + zrow.y * zrow.y + zrow.z * zrow.z + zrow.w * zrow.w;
        s2 += __shfl_xor(s2, 16, 64); s2 += __shfl_xor(s2, 32, 64);
        q2 += __shfl_xor(q2, 16, 64); q2 += __shfl_xor(q2, 32, 64);
        if (g == 0) { ln2s[fw][n16][0] = s2; ln2s[fw][n16][1] = q2; }
    }
    __syncthreads();
    if (fact) {
        const float ts = ln2s[0][n16][0] + ln2s[1][n16][0]
                       + ln2s[2][n16][0] + ln2s[3][n16][0];
        const float tq = ln2s[0][n16][1] + ln2s[1][n16][1]
                       + ln2s[2][n16][1] + ln2s[3][n16][1];
        const float mu2 = ts * (1.f / 64.f);
        const float var2 = tq * (1.f / 64.f) - mu2 * mu2;
        const float rs2 = rsqrtf(var2 + LN_EPS);
        float4 gv  = *(const float4*)&g2[fw * 16 + 4 * g];
        float4 bev = *(const float4*)&be2[fw * 16 + 4 * g];
        float4 yv;
        yv.x = (zrow.x - mu2) * rs2 * gv.x + bev.x;
        yv.y = (zrow.y - mu2) * rs2 * gv.y + bev.y;
        yv.z = (zrow.z - mu2) * rs2 * gv.z + bev.z;
        yv.w = (zrow.w - mu2) * rs2 * gv.w + bev.w;
        *(float4*)&y[row * 64 + fw * 16 + 4 * g] = yv;
    }
}

// ---------------------------------------------------------------------------
extern "C" void kernel_launch(void* const* d_in, const int* in_sizes, int n_in,
                              void* d_out, int out_size, void* d_ws, size_t ws_size,
                              hipStream_t stream) {
    const float* x   = (const float*)d_in[0];
    const int* lengths = (const int*)d_in[1];
    const float* Wq  = (const float*)d_in[3];
    const float* bq  = (const float*)d_in[4];
    const float* Wk  = (const float*)d_in[5];
    const float* bk  = (const float*)d_in[6];
    const float* Wv  = (const float*)d_in[7];
    const float* bv  = (const float*)d_in[8];
    const float* W1  = (const float*)d_in[9];
    const float* b1  = (const float*)d_in[10];
    const float* W2  = (const float*)d_in[11];
    const float* b2  = (const float*)d_in[12];
    const float* g1  = (const float*)d_in[13];
    const float* be1 = (const float*)d_in[14];
    const float* g2  = (const float*)d_in[15];
    const float* be2 = (const float*)d_in[16];

    float* y     = (float*)d_out;                       // [B,S,64]
    float* amean = y + (size_t)NB * NS * NHID;          // [B,S,S]

    const size_t nqkv = (size_t)NB * NHEADS * NS * NDH; // 1,048,576 elems
    _Float16* qhw = (_Float16*)d_ws;                    // f16 [B,NH,S,16] (pre-scaled)
    _Float16* khw = qhw + nqkv;
    _Float16* vtw = khw + nqkv;                         // f16 [B,NH,16,S]

    hipLaunchKernelGGL(qkv_mfma_kernel, dim3(NB * NS / 64), dim3(256), 0, stream,
                       x, Wq, bq, Wk, bk, Wv, bv, qhw, khw, vtw);
    hipLaunchKernelGGL(attn_ffn_kernel, dim3(64, NB), dim3(1024), 0, stream,
                       qhw, khw, vtw, lengths, x,
                       W1, b1, W2, b2, g1, be1, g2, be2,
                       amean, y);
}